// Round 2
// baseline (674.544 us; speedup 1.0000x reference)
//
#include <hip/hip_runtime.h>
#include <hip/hip_bf16.h>

// Problem: B=4, S=8192, D_IN=1024, D_OUT=1024. M = B*S = 32768 rows.
// out[m][o] = (s * alpha) * sum_k qx[m][k] * qw[o][k]   (exact int32 dot)
//   s     = max(global_absmax(xn), 1e-8) / 127
//   alpha = kept_sum / max(kept_cnt, 1),  mask = |w| > 0.7*mean|w|
// All scalar reductions are DETERMINISTIC (double partials + f64 atomics /
// integer atomics) so every launch (incl. graph replays) produces bitwise
// identical output — required by the harness post-timing re-validation.

#define M_ROWS   32768
#define D_IN     1024
#define D_OUT    1024
#define W_ELEMS  (1024*1024)

typedef __attribute__((ext_vector_type(4))) int int4v;

// ---------------- workspace layout (bytes) ----------------
// @0  : u32 absmax_bits
// @4  : u32 kept_cnt
// @8  : f64 sumw
// @16 : f64 kept_sum
// [1024]    : mu   [32768] f32  (128 KB)
// [132096]  : rstd [32768] f32  (128 KB)
// [263168]  : qw   [1024*1024] i8 (1 MB)
// [1311744] : qx   [32768*1024] i8 (32 MB)

// ---------------- K1: LayerNorm stats + global absmax ----------------
__global__ __launch_bounds__(256) void ln_stats_kernel(
    const float* __restrict__ x, const float* __restrict__ gamma,
    const float* __restrict__ beta, float* __restrict__ mu_out,
    float* __restrict__ rstd_out, unsigned int* __restrict__ absmax_bits) {
  int r = blockIdx.x;
  int t = threadIdx.x;
  int wave = t >> 6, lane = t & 63;
  float4 v = ((const float4*)(x + (size_t)r * D_IN))[t];
  float s  = v.x + v.y + v.z + v.w;
  float sq = v.x*v.x + v.y*v.y + v.z*v.z + v.w*v.w;
  #pragma unroll
  for (int off = 32; off; off >>= 1) {
    s  += __shfl_down(s,  off, 64);
    sq += __shfl_down(sq, off, 64);
  }
  __shared__ float ls[4], lq[4], lm[4];
  __shared__ float smu, srstd;
  if (lane == 0) { ls[wave] = s; lq[wave] = sq; }
  __syncthreads();
  if (t == 0) {
    float S = ls[0] + ls[1] + ls[2] + ls[3];
    float Q = lq[0] + lq[1] + lq[2] + lq[3];
    float mu  = S * (1.0f / D_IN);
    float var = Q * (1.0f / D_IN) - mu * mu;
    float rstd = rsqrtf(var + 1e-5f);
    smu = mu; srstd = rstd;
    mu_out[r] = mu; rstd_out[r] = rstd;
  }
  __syncthreads();
  float mu = smu, rstd = srstd;
  float4 g = ((const float4*)gamma)[t];
  float4 b = ((const float4*)beta)[t];
  float nx = (v.x - mu) * rstd * g.x + b.x;
  float ny = (v.y - mu) * rstd * g.y + b.y;
  float nz = (v.z - mu) * rstd * g.z + b.z;
  float nw = (v.w - mu) * rstd * g.w + b.w;
  float am = fmaxf(fmaxf(fabsf(nx), fabsf(ny)), fmaxf(fabsf(nz), fabsf(nw)));
  #pragma unroll
  for (int off = 32; off; off >>= 1) am = fmaxf(am, __shfl_down(am, off, 64));
  if (lane == 0) lm[wave] = am;
  __syncthreads();
  if (t == 0) {
    float m = fmaxf(fmaxf(lm[0], lm[1]), fmaxf(lm[2], lm[3]));
    atomicMax(absmax_bits, __float_as_uint(m));  // m >= 0: uint order == float order; order-independent
  }
}

// ---------------- K2: sum |w| (deterministic: f64 partials + f64 atomic) ----
__global__ __launch_bounds__(256) void w_sum_kernel(const float* __restrict__ w,
                                                    double* __restrict__ sumw) {
  int i = blockIdx.x * 256 + threadIdx.x;
  float4 v = ((const float4*)w)[i];
  double s = (double)fabsf(v.x) + (double)fabsf(v.y) +
             (double)fabsf(v.z) + (double)fabsf(v.w);
  #pragma unroll
  for (int off = 32; off; off >>= 1) s += __shfl_down(s, off, 64);
  __shared__ double ls[4];
  int wave = threadIdx.x >> 6, lane = threadIdx.x & 63;
  if (lane == 0) ls[wave] = s;
  __syncthreads();
  if (threadIdx.x == 0) atomicAdd(sumw, ls[0] + ls[1] + ls[2] + ls[3]);
}

// ---------------- K3: ternary-quantize weights (deterministic) -------------
__global__ __launch_bounds__(256) void w_quant_kernel(
    const float* __restrict__ w, const double* __restrict__ sumw,
    signed char* __restrict__ qw, double* __restrict__ kept_sum,
    unsigned int* __restrict__ kept_cnt) {
  double delta = 0.7 * (*sumw) * (1.0 / (double)W_ELEMS);
  int i = blockIdx.x * 256 + threadIdx.x;
  float4 v = ((const float4*)w)[i];
  double ks = 0.0;
  int kc = 0;
  char4 q;
  {
    double a = (double)fabsf(v.x); bool m = a > delta;
    q.x = m ? (v.x > 0.0f ? 1 : -1) : 0; if (m) { ks += a; kc++; }
  }
  {
    double a = (double)fabsf(v.y); bool m = a > delta;
    q.y = m ? (v.y > 0.0f ? 1 : -1) : 0; if (m) { ks += a; kc++; }
  }
  {
    double a = (double)fabsf(v.z); bool m = a > delta;
    q.z = m ? (v.z > 0.0f ? 1 : -1) : 0; if (m) { ks += a; kc++; }
  }
  {
    double a = (double)fabsf(v.w); bool m = a > delta;
    q.w = m ? (v.w > 0.0f ? 1 : -1) : 0; if (m) { ks += a; kc++; }
  }
  ((char4*)qw)[i] = q;
  #pragma unroll
  for (int off = 32; off; off >>= 1) {
    ks += __shfl_down(ks, off, 64);
    kc += __shfl_down(kc, off, 64);
  }
  __shared__ double lss[4];
  __shared__ int    lcc[4];
  int wave = threadIdx.x >> 6, lane = threadIdx.x & 63;
  if (lane == 0) { lss[wave] = ks; lcc[wave] = kc; }
  __syncthreads();
  if (threadIdx.x == 0) {
    atomicAdd(kept_sum, lss[0] + lss[1] + lss[2] + lss[3]);
    atomicAdd(kept_cnt, (unsigned int)(lcc[0] + lcc[1] + lcc[2] + lcc[3]));
  }
}

// ---------------- K4: quantize activations to int8 ----------------
__global__ __launch_bounds__(256) void act_quant_kernel(
    const float* __restrict__ x, const float* __restrict__ gamma,
    const float* __restrict__ beta, const float* __restrict__ mu_arr,
    const float* __restrict__ rstd_arr,
    const unsigned int* __restrict__ absmax_bits, signed char* __restrict__ qx) {
  int r = blockIdx.x;
  int t = threadIdx.x;
  float am = __uint_as_float(*absmax_bits);
  float scale = fmaxf(am, 1e-8f) / 127.0f;   // mimic np: divide by scale
  float mu = mu_arr[r], rstd = rstd_arr[r];
  float4 v = ((const float4*)(x + (size_t)r * D_IN))[t];
  float4 g = ((const float4*)gamma)[t];
  float4 b = ((const float4*)beta)[t];
  float nx = ((v.x - mu) * rstd * g.x + b.x) / scale;
  float ny = ((v.y - mu) * rstd * g.y + b.y) / scale;
  float nz = ((v.z - mu) * rstd * g.z + b.z) / scale;
  float nw = ((v.w - mu) * rstd * g.w + b.w) / scale;
  char4 q;
  q.x = (signed char)(int)rintf(fminf(fmaxf(nx, -127.0f), 127.0f));
  q.y = (signed char)(int)rintf(fminf(fmaxf(ny, -127.0f), 127.0f));
  q.z = (signed char)(int)rintf(fminf(fmaxf(nz, -127.0f), 127.0f));
  q.w = (signed char)(int)rintf(fminf(fmaxf(nw, -127.0f), 127.0f));
  ((char4*)(qx + (size_t)r * D_IN))[t] = q;
}

// ---------------- K5: int8 GEMM, 128x128 tile, BK=64, swizzled LDS ---------
__device__ inline void async_copy16(const void* g, void* l) {
  __builtin_amdgcn_global_load_lds(
      (const __attribute__((address_space(1))) unsigned int*)g,
      (__attribute__((address_space(3))) unsigned int*)l, 16, 0, 0);
}

__global__ __launch_bounds__(256) void gemm_i8_kernel(
    const signed char* __restrict__ A,   // qx [32768][1024]
    const signed char* __restrict__ B,   // qw [1024][1024] (row = out feature)
    float* __restrict__ C,               // [32768][1024]
    const unsigned int* __restrict__ absmax_bits,
    const double* __restrict__ kept_sum, const unsigned int* __restrict__ kept_cnt) {
  __shared__ __align__(16) signed char sA[128 * 64];
  __shared__ __align__(16) signed char sB[128 * 64];
  int t = threadIdx.x;
  int wave = t >> 6, lane = t & 63;
  int m0 = blockIdx.y * 128;
  int n0 = blockIdx.x * 128;
  int wr = (wave >> 1) * 64;   // wave row offset in tile
  int wc = (wave & 1) * 64;    // wave col offset in tile

  int4v acc[4][4] = {};

  // staging: thread t fills LDS slot t*16 (HW: wave-uniform base + lane*16).
  // LDS row = t>>2 (64B), slot = t&3 (16B chunk). Swizzle: slot s of row r
  // holds global k-chunk g = (s - (r>>1)) & 3  (so fragment reads spread
  // across all 8 16B-bank-groups -> conflict-free 2-way).
  int row_st = t >> 2;          // 0..63
  int slot   = t & 3;
  int kg     = (slot - (row_st >> 1)) & 3;
  const signed char* Ag = A + (size_t)(m0 + row_st) * D_IN + kg * 16;
  const signed char* Bg = B + (size_t)(n0 + row_st) * D_IN + kg * 16;
  signed char* sAp = sA + t * 16;
  signed char* sBp = sB + t * 16;
  // second-half rows r+64: (r+64)>>1 = (r>>1)+32, +32 == 0 (mod 4) -> same kg

  int lrow = lane & 15;
  int c    = lane >> 4;         // which global 16B k-chunk this lane needs

  for (int k0 = 0; k0 < D_IN; k0 += 64) {
    async_copy16(Ag + k0, sAp);
    async_copy16(Ag + k0 + (size_t)64 * D_IN, sAp + 64 * 64);
    async_copy16(Bg + k0, sBp);
    async_copy16(Bg + k0 + (size_t)64 * D_IN, sBp + 64 * 64);
    __syncthreads();   // compiler drains vmcnt before s_barrier

    int4v af[4], bf[4];
    #pragma unroll
    for (int i = 0; i < 4; i++) {
      int r = wr + i * 16 + lrow;
      af[i] = *(const int4v*)(sA + r * 64 + (((c + (r >> 1)) & 3) * 16));
    }
    #pragma unroll
    for (int j = 0; j < 4; j++) {
      int r = wc + j * 16 + lrow;
      bf[j] = *(const int4v*)(sB + r * 64 + (((c + (r >> 1)) & 3) * 16));
    }
    #pragma unroll
    for (int i = 0; i < 4; i++)
      #pragma unroll
      for (int j = 0; j < 4; j++)
        acc[i][j] = __builtin_amdgcn_mfma_i32_16x16x64_i8(af[i], bf[j], acc[i][j], 0, 0, 0);
    __syncthreads();
  }

  float am = __uint_as_float(*absmax_bits);
  double alpha = (*kept_sum) / (double)max(*kept_cnt, 1u);
  float f = (float)(((double)fmaxf(am, 1e-8f) / 127.0) * alpha);

  int crow = m0 + wr + ((lane >> 4) << 2);
  int ccol = n0 + wc + (lane & 15);
  #pragma unroll
  for (int i = 0; i < 4; i++)
    #pragma unroll
    for (int j = 0; j < 4; j++)
      #pragma unroll
      for (int rr = 0; rr < 4; rr++) {
        int row = crow + i * 16 + rr;
        int col = ccol + j * 16;
        C[(size_t)row * D_OUT + col] = (float)acc[i][j][rr] * f;
      }
}

extern "C" void kernel_launch(void* const* d_in, const int* in_sizes, int n_in,
                              void* d_out, int out_size, void* d_ws, size_t ws_size,
                              hipStream_t stream) {
  const float* x     = (const float*)d_in[0];
  const float* w     = (const float*)d_in[1];
  const float* gamma = (const float*)d_in[2];
  const float* beta  = (const float*)d_in[3];
  float* out = (float*)d_out;

  char* ws = (char*)d_ws;
  unsigned int* absmax_bits = (unsigned int*)ws;        // @0
  unsigned int* kept_cnt    = (unsigned int*)(ws + 4);  // @4
  double* sumw     = (double*)(ws + 8);                 // @8
  double* kept_sum = (double*)(ws + 16);                // @16
  float* mu   = (float*)(ws + 1024);
  float* rstd = (float*)(ws + 132096);
  signed char* qw = (signed char*)(ws + 263168);
  signed char* qx = (signed char*)(ws + 1311744);

  hipMemsetAsync(d_ws, 0, 64, stream);  // zero the scalar accumulators

  ln_stats_kernel<<<M_ROWS, 256, 0, stream>>>(x, gamma, beta, mu, rstd, absmax_bits);
  w_sum_kernel<<<W_ELEMS / 1024, 256, 0, stream>>>(w, sumw);
  w_quant_kernel<<<W_ELEMS / 1024, 256, 0, stream>>>(w, sumw, qw, kept_sum, kept_cnt);
  act_quant_kernel<<<M_ROWS, 256, 0, stream>>>(x, gamma, beta, mu, rstd, absmax_bits, qx);

  dim3 grid(D_OUT / 128, M_ROWS / 128);
  gemm_i8_kernel<<<grid, 256, 0, stream>>>(qx, qw, out, absmax_bits, kept_sum, kept_cnt);
}

// Round 3
// 320.755 us; speedup vs baseline: 2.1030x; 2.1030x over previous
//
#include <hip/hip_runtime.h>
#include <hip/hip_bf16.h>

// Problem: B=4, S=8192, D_IN=1024, D_OUT=1024. M = B*S = 32768 rows.
// out[m][o] = (s * alpha) * sum_k qx[m][k] * qw[o][k]   (exact int32 dot)
// Determinism: f64 partials + f64/int atomics for scalar reductions (order
// jitter < 1e-13 rel -> no ternary mask flips across graph replays).
// Atomic discipline: <= 1 same-address atomic per BLOCK, and block counts
// kept small (single-address atomics serialize ~10ns each; 32768 of them
// cost 360us — measured in R1's ln_stats at 379us / 2.3% HBM).

#define M_ROWS   32768
#define D_IN     1024
#define D_OUT    1024
#define W_ELEMS  (1024*1024)

typedef __attribute__((ext_vector_type(4))) int int4v;

// ---------------- workspace layout (bytes) ----------------
// @0  : u32 absmax_bits
// @4  : u32 kept_cnt
// @8  : f64 sumw
// @16 : f64 kept_sum
// [1024]    : mu   [32768] f32  (128 KB)
// [132096]  : rstd [32768] f32  (128 KB)
// [263168]  : qw   [1024*1024] i8 (1 MB)
// [1311744] : qx   [32768*1024] i8 (32 MB)

// ---------------- K1: LayerNorm stats + global absmax ----------------
// 1024 blocks x 4 waves; each wave owns 8 rows (row = wave_gid + 4096*i).
// Butterfly XOR reductions (all lanes get result, no LDS broadcast).
// One atomicMax per block.
__global__ __launch_bounds__(256) void ln_stats_kernel(
    const float* __restrict__ x, const float* __restrict__ gamma,
    const float* __restrict__ beta, float* __restrict__ mu_out,
    float* __restrict__ rstd_out, unsigned int* __restrict__ absmax_bits) {
  int t = threadIdx.x;
  int wave = t >> 6, lane = t & 63;
  int wgid = blockIdx.x * 4 + wave;   // 0..4095

  float4 g[4], b[4];
  #pragma unroll
  for (int k = 0; k < 4; k++) {
    g[k] = ((const float4*)gamma)[lane + 64 * k];
    b[k] = ((const float4*)beta )[lane + 64 * k];
  }

  float amax = 0.0f;
  #pragma unroll 2
  for (int i = 0; i < 8; i++) {
    int row = wgid + 4096 * i;
    const float4* xr = (const float4*)(x + (size_t)row * D_IN);
    float4 v[4];
    #pragma unroll
    for (int k = 0; k < 4; k++) v[k] = xr[lane + 64 * k];
    float s = 0.0f, sq = 0.0f;
    #pragma unroll
    for (int k = 0; k < 4; k++) {
      s  += v[k].x + v[k].y + v[k].z + v[k].w;
      sq += v[k].x*v[k].x + v[k].y*v[k].y + v[k].z*v[k].z + v[k].w*v[k].w;
    }
    #pragma unroll
    for (int off = 1; off < 64; off <<= 1) {
      s  += __shfl_xor(s,  off, 64);
      sq += __shfl_xor(sq, off, 64);
    }
    float mu   = s * (1.0f / D_IN);
    float var  = sq * (1.0f / D_IN) - mu * mu;
    float rstd = rsqrtf(var + 1e-5f);
    if (lane == 0) { mu_out[row] = mu; rstd_out[row] = rstd; }
    #pragma unroll
    for (int k = 0; k < 4; k++) {
      float nx = (v[k].x - mu) * rstd * g[k].x + b[k].x;
      float ny = (v[k].y - mu) * rstd * g[k].y + b[k].y;
      float nz = (v[k].z - mu) * rstd * g[k].z + b[k].z;
      float nw = (v[k].w - mu) * rstd * g[k].w + b[k].w;
      amax = fmaxf(amax, fmaxf(fmaxf(fabsf(nx), fabsf(ny)),
                               fmaxf(fabsf(nz), fabsf(nw))));
    }
  }
  #pragma unroll
  for (int off = 1; off < 64; off <<= 1)
    amax = fmaxf(amax, __shfl_xor(amax, off, 64));
  __shared__ float wm[4];
  if (lane == 0) wm[wave] = amax;
  __syncthreads();
  if (t == 0) {
    float m = fmaxf(fmaxf(wm[0], wm[1]), fmaxf(wm[2], wm[3]));
    atomicMax(absmax_bits, __float_as_uint(m));  // m>=0: uint order == float order
  }
}

// ---------------- K2: sum |w| — 256 blocks, 4 float4/thread ----------------
__global__ __launch_bounds__(256) void w_sum_kernel(const float* __restrict__ w,
                                                    double* __restrict__ sumw) {
  int base = blockIdx.x * 1024 + threadIdx.x;
  double s = 0.0;
  #pragma unroll
  for (int j = 0; j < 4; j++) {
    float4 v = ((const float4*)w)[base + 256 * j];
    s += (double)fabsf(v.x) + (double)fabsf(v.y) +
         (double)fabsf(v.z) + (double)fabsf(v.w);
  }
  #pragma unroll
  for (int off = 1; off < 64; off <<= 1) s += __shfl_xor(s, off, 64);
  __shared__ double ls[4];
  int wave = threadIdx.x >> 6, lane = threadIdx.x & 63;
  if (lane == 0) ls[wave] = s;
  __syncthreads();
  if (threadIdx.x == 0) atomicAdd(sumw, ls[0] + ls[1] + ls[2] + ls[3]);
}

// ---------------- K3: ternary-quantize weights — 256 blocks ----------------
__global__ __launch_bounds__(256) void w_quant_kernel(
    const float* __restrict__ w, const double* __restrict__ sumw,
    signed char* __restrict__ qw, double* __restrict__ kept_sum,
    unsigned int* __restrict__ kept_cnt) {
  double delta = 0.7 * (*sumw) * (1.0 / (double)W_ELEMS);
  int base = blockIdx.x * 1024 + threadIdx.x;
  double ks = 0.0;
  int kc = 0;
  #pragma unroll
  for (int j = 0; j < 4; j++) {
    float4 v = ((const float4*)w)[base + 256 * j];
    char4 q;
    {
      double a = (double)fabsf(v.x); bool m = a > delta;
      q.x = m ? (v.x > 0.0f ? 1 : -1) : 0; if (m) { ks += a; kc++; }
    }
    {
      double a = (double)fabsf(v.y); bool m = a > delta;
      q.y = m ? (v.y > 0.0f ? 1 : -1) : 0; if (m) { ks += a; kc++; }
    }
    {
      double a = (double)fabsf(v.z); bool m = a > delta;
      q.z = m ? (v.z > 0.0f ? 1 : -1) : 0; if (m) { ks += a; kc++; }
    }
    {
      double a = (double)fabsf(v.w); bool m = a > delta;
      q.w = m ? (v.w > 0.0f ? 1 : -1) : 0; if (m) { ks += a; kc++; }
    }
    ((char4*)qw)[base + 256 * j] = q;
  }
  #pragma unroll
  for (int off = 1; off < 64; off <<= 1) {
    ks += __shfl_xor(ks, off, 64);
    kc += __shfl_xor(kc, off, 64);
  }
  __shared__ double lss[4];
  __shared__ int    lcc[4];
  int wave = threadIdx.x >> 6, lane = threadIdx.x & 63;
  if (lane == 0) { lss[wave] = ks; lcc[wave] = kc; }
  __syncthreads();
  if (threadIdx.x == 0) {
    atomicAdd(kept_sum, lss[0] + lss[1] + lss[2] + lss[3]);
    atomicAdd(kept_cnt, (unsigned int)(lcc[0] + lcc[1] + lcc[2] + lcc[3]));
  }
}

// ---------------- K4: quantize activations — 2048 blocks x 16 rows ---------
__global__ __launch_bounds__(256) void act_quant_kernel(
    const float* __restrict__ x, const float* __restrict__ gamma,
    const float* __restrict__ beta, const float* __restrict__ mu_arr,
    const float* __restrict__ rstd_arr,
    const unsigned int* __restrict__ absmax_bits, signed char* __restrict__ qx) {
  int t = threadIdx.x;
  float am = __uint_as_float(*absmax_bits);
  float scale = fmaxf(am, 1e-8f) / 127.0f;
  float4 g = ((const float4*)gamma)[t];
  float4 b = ((const float4*)beta)[t];
  #pragma unroll 2
  for (int i = 0; i < 16; i++) {
    int row = blockIdx.x * 16 + i;
    float mu = mu_arr[row], rstd = rstd_arr[row];
    float4 v = ((const float4*)(x + (size_t)row * D_IN))[t];
    float nx = ((v.x - mu) * rstd * g.x + b.x) / scale;
    float ny = ((v.y - mu) * rstd * g.y + b.y) / scale;
    float nz = ((v.z - mu) * rstd * g.z + b.z) / scale;
    float nw = ((v.w - mu) * rstd * g.w + b.w) / scale;
    char4 q;
    q.x = (signed char)(int)rintf(fminf(fmaxf(nx, -127.0f), 127.0f));
    q.y = (signed char)(int)rintf(fminf(fmaxf(ny, -127.0f), 127.0f));
    q.z = (signed char)(int)rintf(fminf(fmaxf(nz, -127.0f), 127.0f));
    q.w = (signed char)(int)rintf(fminf(fmaxf(nw, -127.0f), 127.0f));
    ((char4*)(qx + (size_t)row * D_IN))[t] = q;
  }
}

// ---------------- K5: int8 GEMM, 128x128 tile, BK=64, swizzled LDS ---------
__device__ inline void async_copy16(const void* g, void* l) {
  __builtin_amdgcn_global_load_lds(
      (const __attribute__((address_space(1))) unsigned int*)g,
      (__attribute__((address_space(3))) unsigned int*)l, 16, 0, 0);
}

__global__ __launch_bounds__(256) void gemm_i8_kernel(
    const signed char* __restrict__ A,   // qx [32768][1024]
    const signed char* __restrict__ B,   // qw [1024][1024] (row = out feature)
    float* __restrict__ C,               // [32768][1024]
    const unsigned int* __restrict__ absmax_bits,
    const double* __restrict__ kept_sum, const unsigned int* __restrict__ kept_cnt) {
  __shared__ __align__(16) signed char sA[128 * 64];
  __shared__ __align__(16) signed char sB[128 * 64];
  int t = threadIdx.x;
  int wave = t >> 6, lane = t & 63;
  int m0 = blockIdx.y * 128;
  int n0 = blockIdx.x * 128;
  int wr = (wave >> 1) * 64;
  int wc = (wave & 1) * 64;

  int4v acc[4][4] = {};

  int row_st = t >> 2;
  int slot   = t & 3;
  int kg     = (slot - (row_st >> 1)) & 3;   // XOR-rotate swizzle of 16B chunks
  const signed char* Ag = A + (size_t)(m0 + row_st) * D_IN + kg * 16;
  const signed char* Bg = B + (size_t)(n0 + row_st) * D_IN + kg * 16;
  signed char* sAp = sA + t * 16;
  signed char* sBp = sB + t * 16;

  int lrow = lane & 15;
  int c    = lane >> 4;

  for (int k0 = 0; k0 < D_IN; k0 += 64) {
    async_copy16(Ag + k0, sAp);
    async_copy16(Ag + k0 + (size_t)64 * D_IN, sAp + 64 * 64);
    async_copy16(Bg + k0, sBp);
    async_copy16(Bg + k0 + (size_t)64 * D_IN, sBp + 64 * 64);
    __syncthreads();

    int4v af[4], bf[4];
    #pragma unroll
    for (int i = 0; i < 4; i++) {
      int r = wr + i * 16 + lrow;
      af[i] = *(const int4v*)(sA + r * 64 + (((c + (r >> 1)) & 3) * 16));
    }
    #pragma unroll
    for (int j = 0; j < 4; j++) {
      int r = wc + j * 16 + lrow;
      bf[j] = *(const int4v*)(sB + r * 64 + (((c + (r >> 1)) & 3) * 16));
    }
    #pragma unroll
    for (int i = 0; i < 4; i++)
      #pragma unroll
      for (int j = 0; j < 4; j++)
        acc[i][j] = __builtin_amdgcn_mfma_i32_16x16x64_i8(af[i], bf[j], acc[i][j], 0, 0, 0);
    __syncthreads();
  }

  float am = __uint_as_float(*absmax_bits);
  double alpha = (*kept_sum) / (double)max(*kept_cnt, 1u);
  float f = (float)(((double)fmaxf(am, 1e-8f) / 127.0) * alpha);

  int crow = m0 + wr + ((lane >> 4) << 2);
  int ccol = n0 + wc + (lane & 15);
  #pragma unroll
  for (int i = 0; i < 4; i++)
    #pragma unroll
    for (int j = 0; j < 4; j++)
      #pragma unroll
      for (int rr = 0; rr < 4; rr++) {
        int row = crow + i * 16 + rr;
        int col = ccol + j * 16;
        C[(size_t)row * D_OUT + col] = (float)acc[i][j][rr] * f;
      }
}

extern "C" void kernel_launch(void* const* d_in, const int* in_sizes, int n_in,
                              void* d_out, int out_size, void* d_ws, size_t ws_size,
                              hipStream_t stream) {
  const float* x     = (const float*)d_in[0];
  const float* w     = (const float*)d_in[1];
  const float* gamma = (const float*)d_in[2];
  const float* beta  = (const float*)d_in[3];
  float* out = (float*)d_out;

  char* ws = (char*)d_ws;
  unsigned int* absmax_bits = (unsigned int*)ws;        // @0
  unsigned int* kept_cnt    = (unsigned int*)(ws + 4);  // @4
  double* sumw     = (double*)(ws + 8);                 // @8
  double* kept_sum = (double*)(ws + 16);                // @16
  float* mu   = (float*)(ws + 1024);
  float* rstd = (float*)(ws + 132096);
  signed char* qw = (signed char*)(ws + 263168);
  signed char* qx = (signed char*)(ws + 1311744);

  hipMemsetAsync(d_ws, 0, 64, stream);

  ln_stats_kernel<<<1024, 256, 0, stream>>>(x, gamma, beta, mu, rstd, absmax_bits);
  w_sum_kernel<<<256, 256, 0, stream>>>(w, sumw);
  w_quant_kernel<<<256, 256, 0, stream>>>(w, sumw, qw, kept_sum, kept_cnt);
  act_quant_kernel<<<2048, 256, 0, stream>>>(x, gamma, beta, mu, rstd, absmax_bits, qx);

  dim3 grid(D_OUT / 128, M_ROWS / 128);
  gemm_i8_kernel<<<grid, 256, 0, stream>>>(qx, qw, out, absmax_bits, kept_sum, kept_cnt);
}